// Round 2
// baseline (1069.852 us; speedup 1.0000x reference)
//
#include <hip/hip_runtime.h>
#include <math.h>

#define D        144
#define KPAD     160
#define KCODES   50257
#define NROWS    4096
#define NS       16
#define CHUNK    3142        // ceil(50257/16)
#define CAP      1024
#define MARGIN   3.0e-5f
#define ZQ_OFF   0
#define IDX_OFF  589824
#define LOSS_OFF 593920

typedef short bf16x8 __attribute__((ext_vector_type(8)));
typedef float f32x4  __attribute__((ext_vector_type(4)));

// ws layout (main path)
#define EH_OFF   0
#define EH_SZ    ((size_t)KCODES * KPAD * 2)            // 16,082,240
#define EL_OFF   (EH_OFF + EH_SZ)
#define CNT_OFF  (EL_OFF + EH_SZ)                        // 32,164,480
#define CNT_SZ   ((size_t)NROWS * 4)
#define LIST_OFF (CNT_OFF + CNT_SZ)
#define LIST_SZ  ((size_t)NROWS * CAP * 4)
#define LROW_OFF (LIST_OFF + LIST_SZ)
#define WS_NEED  (LROW_OFF + (size_t)NROWS * 4)          // ~46.7 MiB

static __device__ __forceinline__ unsigned short f2bf(float x) {
    unsigned int u = __float_as_uint(x);
    u += 0x7fffu + ((u >> 16) & 1u);   // RNE
    return (unsigned short)(u >> 16);
}
static __device__ __forceinline__ float bf2f(unsigned short b) {
    return __uint_as_float(((unsigned int)b) << 16);
}

// ---------------- prep: emb fp32 -> bf16 hi/lo, K padded to 160 --------------
__global__ void prep_emb_kernel(const float* __restrict__ emb,
                                unsigned short* __restrict__ EH,
                                unsigned short* __restrict__ EL) {
    const int idx = blockIdx.x * 256 + threadIdx.x;   // code*20 + chunk
    if (idx >= KCODES * 20) return;
    const int code = idx / 20;
    const int k0   = (idx % 20) * 8;
    unsigned short h[8], l[8];
    if (k0 < D) {
        const float4 f0 = *(const float4*)(emb + (size_t)code * D + k0);
        const float4 f1 = *(const float4*)(emb + (size_t)code * D + k0 + 4);
        const float f[8] = {f0.x, f0.y, f0.z, f0.w, f1.x, f1.y, f1.z, f1.w};
        #pragma unroll
        for (int j = 0; j < 8; ++j) {
            h[j] = f2bf(f[j]);
            l[j] = f2bf(f[j] - bf2f(h[j]));   // f - hi exact in fp32
        }
    } else {
        #pragma unroll
        for (int j = 0; j < 8; ++j) { h[j] = 0; l[j] = 0; }
    }
    const size_t o = (size_t)code * KPAD + k0;
    *(uint4*)(EH + o) = *(const uint4*)h;
    *(uint4*)(EL + o) = *(const uint4*)l;
}

__global__ void zero_cnt_kernel(int* __restrict__ cnt) {
    const int i = blockIdx.x * 256 + threadIdx.x;
    if (i < NROWS) cnt[i] = 0;
}

// ------------- phase A: 3-pass bf16 MFMA, per-wave row-max + select ----------
// grid(64 row-blocks, NS splits), 256 thr (4 waves). Wave w = codes w*16..w*16+15
// of each 64-code tile. A-frags (z) in registers; B-frags direct global loads.
__global__ __launch_bounds__(256, 2)
void vq_phaseA_kernel(const float* __restrict__ z,
                      const unsigned short* __restrict__ EH,
                      const unsigned short* __restrict__ EL,
                      int* __restrict__ cnt, int* __restrict__ list) {
    const int tid  = threadIdx.x;
    const int w    = tid >> 6;
    const int lane = tid & 63;
    const int n    = lane & 15;     // A: m-index on read; D: col (code)
    const int q    = lane >> 4;     // quad
    const int row0 = blockIdx.x * 64;
    const int sp   = blockIdx.y;
    const int c0   = sp * CHUNK;
    const int c1   = (c0 + CHUNK < KCODES) ? (c0 + CHUNK) : KCODES;

    // ---- A fragments: A[m=lane&15][k=quad*8+j], bf16 hi/lo, K padded ----
    bf16x8 Ah[4][5], Al[4][5];
    #pragma unroll
    for (int rt = 0; rt < 4; ++rt) {
        const float* zr = z + (size_t)(row0 + rt * 16 + n) * D;
        #pragma unroll
        for (int ks = 0; ks < 5; ++ks) {
            const int k0 = ks * 32 + q * 8;
            bf16x8 h, l;
            if (k0 < D) {
                const float4 f0 = *(const float4*)(zr + k0);
                const float4 f1 = *(const float4*)(zr + k0 + 4);
                const float f[8] = {f0.x, f0.y, f0.z, f0.w, f1.x, f1.y, f1.z, f1.w};
                #pragma unroll
                for (int j = 0; j < 8; ++j) {
                    const unsigned short hb = f2bf(f[j]);
                    h[j] = (short)hb;
                    l[j] = (short)f2bf(f[j] - bf2f(hb));
                }
            } else {
                #pragma unroll
                for (int j = 0; j < 8; ++j) { h[j] = 0; l[j] = 0; }
            }
            Ah[rt][ks] = h; Al[rt][ks] = l;
        }
    }

    float ml[16];
    #pragma unroll
    for (int i = 0; i < 16; ++i) ml[i] = -INFINITY;

    const int ntiles = (c1 - c0 + 63) >> 6;
    for (int t = 0; t < ntiles; ++t) {
        const int cb    = c0 + t * 64;
        const int code  = cb + w * 16 + n;
        const int codeL = (code < KCODES) ? code : (KCODES - 1);
        const unsigned short* ph = EH + (size_t)codeL * KPAD;
        const unsigned short* pl = EL + (size_t)codeL * KPAD;

        f32x4 acc[4];
        #pragma unroll
        for (int rt = 0; rt < 4; ++rt) { acc[rt][0]=0.f; acc[rt][1]=0.f; acc[rt][2]=0.f; acc[rt][3]=0.f; }

        #pragma unroll
        for (int ks = 0; ks < 5; ++ks) {
            const int k0 = ks * 32 + q * 8;
            const bf16x8 bh = *(const bf16x8*)(ph + k0);
            const bf16x8 bl = *(const bf16x8*)(pl + k0);
            #pragma unroll
            for (int rt = 0; rt < 4; ++rt)
                acc[rt] = __builtin_amdgcn_mfma_f32_16x16x32_bf16(Ah[rt][ks], bh, acc[rt], 0, 0, 0);
            #pragma unroll
            for (int rt = 0; rt < 4; ++rt)
                acc[rt] = __builtin_amdgcn_mfma_f32_16x16x32_bf16(Al[rt][ks], bh, acc[rt], 0, 0, 0);
            #pragma unroll
            for (int rt = 0; rt < 4; ++rt)
                acc[rt] = __builtin_amdgcn_mfma_f32_16x16x32_bf16(Ah[rt][ks], bl, acc[rt], 0, 0, 0);
        }

        const bool valid = (code < c1);
        #pragma unroll
        for (int rt = 0; rt < 4; ++rt) {
            #pragma unroll
            for (int r = 0; r < 4; ++r) {
                // D[m=q*4+r][n=lane&15]: row = row0+rt*16+q*4+r, col/code = cb+w*16+n
                const float vm = valid ? (2.0f * acc[rt][r]) : -INFINITY;
                float tm = vm;
                tm = fmaxf(tm, __shfl_xor(tm, 1, 64));
                tm = fmaxf(tm, __shfl_xor(tm, 2, 64));
                tm = fmaxf(tm, __shfl_xor(tm, 4, 64));
                tm = fmaxf(tm, __shfl_xor(tm, 8, 64));
                const int i = rt * 4 + r;
                const float mlo = fmaxf(ml[i], tm);   // update BEFORE select
                ml[i] = mlo;
                if (vm >= mlo - MARGIN) {
                    const int row = row0 + rt * 16 + q * 4 + r;
                    const int pos = atomicAdd(&cnt[row], 1);
                    if (pos < CAP) list[(size_t)row * CAP + pos] = code;
                }
            }
        }
    }
}

// ------ phase C: exact fp32 re-eval of candidates, tie-break, gather, loss ---
__global__ void vq_phaseC_kernel(const float* __restrict__ z,
                                 const float* __restrict__ emb,
                                 const int* __restrict__ cnt,
                                 const int* __restrict__ list,
                                 float* __restrict__ out,
                                 float* __restrict__ lrow) {
    const int r   = blockIdx.x;
    const int tid = threadIdx.x;
    const int lane = tid & 63, wid = tid >> 6;
    __shared__ float zs[D];
    __shared__ float As_;
    __shared__ float bd_s[4]; __shared__ int bi_s[4];
    __shared__ int   bc_s;
    __shared__ float ls_s[4];

    if (tid < D) zs[tid] = z[(size_t)r * D + tid];
    __syncthreads();
    if (tid == 0) {
        float s = 0.f;
        for (int k = 0; k < D; ++k) s = fmaf(zs[k], zs[k], s);
        As_ = s;
    }
    __syncthreads();
    const float A = As_;

    const int nc   = cnt[r];
    const bool full = (nc <= 0) || (nc > CAP);
    const int count = full ? KCODES : nc;

    float bd = INFINITY; int bi = 0x7fffffff;
    for (int i = tid; i < count; i += 256) {
        const int c = full ? i : list[(size_t)r * CAP + i];
        const float4* e4 = (const float4*)(emb + (size_t)c * D);
        float acc = 0.f;
        #pragma unroll
        for (int j = 0; j < 36; ++j) {
            const float4 e = e4[j];
            acc = fmaf(zs[4*j],   e.x, acc);
            acc = fmaf(zs[4*j+1], e.y, acc);
            acc = fmaf(zs[4*j+2], e.z, acc);
            acc = fmaf(zs[4*j+3], e.w, acc);
        }
        const float m2 = 2.0f * acc;
        const float d  = A - m2;            // identical to verified R1 arithmetic
        if (d < bd || (d == bd && c < bi)) { bd = d; bi = c; }
    }
    #pragma unroll
    for (int m = 1; m < 64; m <<= 1) {
        const float od = __shfl_xor(bd, m, 64);
        const int   oi = __shfl_xor(bi, m, 64);
        if (od < bd || (od == bd && oi < bi)) { bd = od; bi = oi; }
    }
    if (lane == 0) { bd_s[wid] = bd; bi_s[wid] = bi; }
    __syncthreads();
    if (tid == 0) {
        float fbd = bd_s[0]; int fbi = bi_s[0];
        for (int k = 1; k < 4; ++k) {
            if (bd_s[k] < fbd || (bd_s[k] == fbd && bi_s[k] < fbi)) { fbd = bd_s[k]; fbi = bi_s[k]; }
        }
        bc_s = fbi;
        out[IDX_OFF + r] = (float)fbi;
    }
    __syncthreads();
    const int bc = bc_s;

    float ls = 0.f;
    if (tid < D) {
        const float e = emb[(size_t)bc * D + tid];
        out[(size_t)r * D + tid] = e;
        const float dl = e - zs[tid];
        ls = dl * dl;
    }
    #pragma unroll
    for (int m = 1; m < 64; m <<= 1) ls += __shfl_xor(ls, m, 64);
    if (lane == 0) ls_s[wid] = ls;
    __syncthreads();
    if (tid == 0) lrow[r] = ls_s[0] + ls_s[1] + ls_s[2] + ls_s[3];
}

// ---------------------------- final loss reduce ------------------------------
__global__ void vq_loss_kernel(const float* __restrict__ lrow, float* __restrict__ out) {
    __shared__ float sm[256];
    const int tid = threadIdx.x;
    float s = 0.f;
    for (int i = tid; i < NROWS; i += 256) s += lrow[i];
    sm[tid] = s; __syncthreads();
    for (int st = 128; st > 0; st >>= 1) {
        if (tid < st) sm[tid] += sm[tid + st];
        __syncthreads();
    }
    if (tid == 0) out[LOSS_OFF] = sm[0] / 589824.0f;
}

// ======================= R1 fallback (small-ws path) =========================
#define BM 64
#define BN 64
#define LDP 68
__global__ __launch_bounds__(256, 2)
void vq_argmin_fb(const float* __restrict__ z, const float* __restrict__ emb,
                  float* __restrict__ pd, int* __restrict__ pi) {
    __shared__ float zsm[D][LDP];
    __shared__ float esm[D][LDP];
    __shared__ float Asm[BM];
    const int tid = threadIdx.x;
    const int row0 = blockIdx.x * BM;
    const int sp = blockIdx.y;
    const int c0 = sp * CHUNK;
    const int c1 = (c0 + CHUNK < KCODES) ? (c0 + CHUNK) : KCODES;
    {
        const int r = tid >> 2, p = tid & 3;
        const float4* src = (const float4*)(z + (size_t)(row0 + r) * D);
        #pragma unroll
        for (int i = 0; i < 9; ++i) {
            const int j4 = p + 4 * i;
            const float4 v = src[j4];
            zsm[4*j4+0][r] = v.x; zsm[4*j4+1][r] = v.y;
            zsm[4*j4+2][r] = v.z; zsm[4*j4+3][r] = v.w;
        }
    }
    __syncthreads();
    if (tid < BM) {
        float s = 0.f;
        for (int k = 0; k < D; ++k) { const float t = zsm[k][tid]; s = fmaf(t, t, s); }
        Asm[tid] = s;
    }
    __syncthreads();
    const int tx = tid & 15, ty = tid >> 4;
    float Arow[4];
    #pragma unroll
    for (int i = 0; i < 4; ++i) Arow[i] = Asm[ty*4 + i];
    float bestd[4]; int besti[4];
    #pragma unroll
    for (int i = 0; i < 4; ++i) { bestd[i] = INFINITY; besti[i] = 0x7fffffff; }
    const int ntiles = (c1 - c0 + BN - 1) / BN;
    for (int t = 0; t < ntiles; ++t) {
        const int cb = c0 + t * BN;
        __syncthreads();
        {
            const int cl = tid >> 2, p = tid & 3;
            int crow = cb + cl; if (crow >= KCODES) crow = KCODES - 1;
            const float4* src = (const float4*)(emb + (size_t)crow * D);
            #pragma unroll
            for (int i = 0; i < 9; ++i) {
                const int j4 = p + 4 * i;
                const float4 v = src[j4];
                esm[4*j4+0][cl] = v.x; esm[4*j4+1][cl] = v.y;
                esm[4*j4+2][cl] = v.z; esm[4*j4+3][cl] = v.w;
            }
        }
        __syncthreads();
        float acc[4][4];
        #pragma unroll
        for (int i = 0; i < 4; ++i)
            #pragma unroll
            for (int j = 0; j < 4; ++j) acc[i][j] = 0.f;
        #pragma unroll 4
        for (int k = 0; k < D; ++k) {
            const float4 a = *(const float4*)&zsm[k][ty*4];
            const float4 b = *(const float4*)&esm[k][tx*4];
            acc[0][0]=fmaf(a.x,b.x,acc[0][0]); acc[0][1]=fmaf(a.x,b.y,acc[0][1]);
            acc[0][2]=fmaf(a.x,b.z,acc[0][2]); acc[0][3]=fmaf(a.x,b.w,acc[0][3]);
            acc[1][0]=fmaf(a.y,b.x,acc[1][0]); acc[1][1]=fmaf(a.y,b.y,acc[1][1]);
            acc[1][2]=fmaf(a.y,b.z,acc[1][2]); acc[1][3]=fmaf(a.y,b.w,acc[1][3]);
            acc[2][0]=fmaf(a.z,b.x,acc[2][0]); acc[2][1]=fmaf(a.z,b.y,acc[2][1]);
            acc[2][2]=fmaf(a.z,b.z,acc[2][2]); acc[2][3]=fmaf(a.z,b.w,acc[2][3]);
            acc[3][0]=fmaf(a.w,b.x,acc[3][0]); acc[3][1]=fmaf(a.w,b.y,acc[3][1]);
            acc[3][2]=fmaf(a.w,b.z,acc[3][2]); acc[3][3]=fmaf(a.w,b.w,acc[3][3]);
        }
        #pragma unroll
        for (int j = 0; j < 4; ++j) {
            const int code = cb + tx*4 + j;
            if (code < c1) {
                #pragma unroll
                for (int i = 0; i < 4; ++i) {
                    const float m2 = 2.0f * acc[i][j];
                    const float d  = Arow[i] - m2;
                    if (d < bestd[i] || (d == bestd[i] && code < besti[i])) {
                        bestd[i] = d; besti[i] = code;
                    }
                }
            }
        }
    }
    #pragma unroll
    for (int i = 0; i < 4; ++i) {
        float d = bestd[i]; int idx = besti[i];
        #pragma unroll
        for (int m = 1; m < 16; m <<= 1) {
            const float od = __shfl_xor(d, m, 64);
            const int   oi = __shfl_xor(idx, m, 64);
            if (od < d || (od == d && oi < idx)) { d = od; idx = oi; }
        }
        if (tx == 0) {
            const int r = row0 + ty*4 + i;
            pd[(size_t)sp * NROWS + r] = d;
            pi[(size_t)sp * NROWS + r] = idx;
        }
    }
}

__global__ void vq_finalize_fb(const float* __restrict__ z, const float* __restrict__ emb,
                               const float* __restrict__ pd, const int* __restrict__ pi,
                               float* __restrict__ out, float* __restrict__ lrow) {
    const int r = blockIdx.x * blockDim.x + threadIdx.x;
    if (r >= NROWS) return;
    float bd = INFINITY; int bi = 0x7fffffff;
    for (int s = 0; s < NS; ++s) {
        const float d = pd[(size_t)s * NROWS + r];
        const int  ix = pi[(size_t)s * NROWS + r];
        if (d < bd || (d == bd && ix < bi)) { bd = d; bi = ix; }
    }
    out[IDX_OFF + r] = (float)bi;
    const float4* e4 = (const float4*)(emb + (size_t)bi * D);
    const float4* z4 = (const float4*)(z + (size_t)r * D);
    float4* o4 = (float4*)(out + (size_t)r * D);
    float ls = 0.f;
    #pragma unroll
    for (int j = 0; j < 36; ++j) {
        const float4 e = e4[j], zz = z4[j];
        o4[j] = e;
        const float dx = e.x - zz.x, dy = e.y - zz.y;
        const float dz_ = e.z - zz.z, dw = e.w - zz.w;
        ls += dx*dx + dy*dy + dz_*dz_ + dw*dw;
    }
    lrow[r] = ls;
}

// ------------------------------- launch --------------------------------------
extern "C" void kernel_launch(void* const* d_in, const int* in_sizes, int n_in,
                              void* d_out, int out_size, void* d_ws, size_t ws_size,
                              hipStream_t stream) {
    const float* z   = (const float*)d_in[0];
    const float* emb = (const float*)d_in[1];
    float* out = (float*)d_out;

    if (ws_size >= WS_NEED) {
        unsigned short* EH  = (unsigned short*)((char*)d_ws + EH_OFF);
        unsigned short* EL  = (unsigned short*)((char*)d_ws + EL_OFF);
        int*   cnt  = (int*)((char*)d_ws + CNT_OFF);
        int*   list = (int*)((char*)d_ws + LIST_OFF);
        float* lrow = (float*)((char*)d_ws + LROW_OFF);

        prep_emb_kernel<<<(KCODES * 20 + 255) / 256, 256, 0, stream>>>(emb, EH, EL);
        zero_cnt_kernel<<<(NROWS + 255) / 256, 256, 0, stream>>>(cnt);
        dim3 gA(64, NS);
        vq_phaseA_kernel<<<gA, 256, 0, stream>>>(z, EH, EL, cnt, list);
        vq_phaseC_kernel<<<NROWS, 256, 0, stream>>>(z, emb, cnt, list, out, lrow);
        vq_loss_kernel<<<1, 256, 0, stream>>>(lrow, out);
    } else {
        float* pd   = (float*)d_ws;
        int*   pi   = (int*)((char*)d_ws + (size_t)NS * NROWS * 4);
        float* lrow = (float*)((char*)d_ws + (size_t)NS * NROWS * 8);
        dim3 g1(64, NS);
        vq_argmin_fb<<<g1, 256, 0, stream>>>(z, emb, pd, pi);
        vq_finalize_fb<<<16, 256, 0, stream>>>(z, emb, pd, pi, out, lrow);
        vq_loss_kernel<<<1, 256, 0, stream>>>(lrow, out);
    }
}

// Round 3
// 351.711 us; speedup vs baseline: 3.0418x; 3.0418x over previous
//
#include <hip/hip_runtime.h>
#include <math.h>

#define D        144
#define KPAD     160
#define KCODES   50257
#define EHROWS   50400        // covers c0 + 51*64 prefetch overrun; pad rows zero
#define NROWS    4096
#define NS       16
#define CHUNK    3142         // ceil(50257/16)
#define NT       50           // tiles of 64 codes per split (uniform; pad rows absorb)
#define CAP      1024
#define MARGIN   6.0e-5f
#define ZQ_OFF   0
#define IDX_OFF  589824
#define LOSS_OFF 593920

typedef short bf16x8 __attribute__((ext_vector_type(8)));
typedef float f32x4  __attribute__((ext_vector_type(4)));

// ---- ws layout (main path) ----
#define EH_OFF   0
#define EH_SZ    ((size_t)EHROWS * KPAD * 2)             // 16,128,000
#define CNT_OFF  (EH_OFF + EH_SZ)
#define RMX_OFF  (CNT_OFF + (size_t)NROWS * 4)
#define LIST_OFF (RMX_OFF + (size_t)NROWS * 4)
#define LROW_OFF (LIST_OFF + (size_t)NROWS * CAP * 4)
#define WS_NEED  (LROW_OFF + (size_t)NROWS * 4)          // ~31.4 MiB

static __device__ __forceinline__ unsigned short f2bf(float x) {
    unsigned int u = __float_as_uint(x);
    u += 0x7fffu + ((u >> 16) & 1u);   // RNE
    return (unsigned short)(u >> 16);
}
static __device__ __forceinline__ unsigned fkey(float f) {   // monotone float->uint
    unsigned u = __float_as_uint(f);
    return (u & 0x80000000u) ? ~u : (u | 0x80000000u);
}
static __device__ __forceinline__ float fkey_inv(unsigned k) {
    unsigned u = (k & 0x80000000u) ? (k ^ 0x80000000u) : ~k;
    return __uint_as_float(u);
}

// ---------------- prep: emb fp32 -> bf16 hi, K padded, rows padded -----------
__global__ void prep_emb_kernel(const float* __restrict__ emb,
                                unsigned short* __restrict__ EH) {
    const int idx = blockIdx.x * 256 + threadIdx.x;   // code*20 + chunk
    if (idx >= EHROWS * 20) return;
    const int code = idx / 20;
    const int k0   = (idx % 20) * 8;
    unsigned short h[8];
    if (code < KCODES && k0 < D) {
        const float4 f0 = *(const float4*)(emb + (size_t)code * D + k0);
        const float4 f1 = *(const float4*)(emb + (size_t)code * D + k0 + 4);
        const float f[8] = {f0.x, f0.y, f0.z, f0.w, f1.x, f1.y, f1.z, f1.w};
        #pragma unroll
        for (int j = 0; j < 8; ++j) h[j] = f2bf(f[j]);
    } else {
        #pragma unroll
        for (int j = 0; j < 8; ++j) h[j] = 0;
    }
    *(uint4*)(EH + (size_t)code * KPAD + k0) = *(const uint4*)h;
}

__global__ void zero_ws_kernel(int* __restrict__ cnt, unsigned* __restrict__ rmx) {
    const int i = blockIdx.x * 256 + threadIdx.x;
    if (i < NROWS) { cnt[i] = 0; rmx[i] = 0u; }
}

// ---------------- shared helper: load A fragments (z -> bf16 hi) -------------
static __device__ __forceinline__ void load_A_frags(const float* __restrict__ z,
                                                    int row0, int n, int q,
                                                    bf16x8 Ah[4][5]) {
    #pragma unroll
    for (int rt = 0; rt < 4; ++rt) {
        const float* zr = z + (size_t)(row0 + rt * 16 + n) * D;
        #pragma unroll
        for (int ks = 0; ks < 5; ++ks) {
            const int k0 = ks * 32 + q * 8;
            bf16x8 h;
            if (k0 < D) {
                const float4 f0 = *(const float4*)(zr + k0);
                const float4 f1 = *(const float4*)(zr + k0 + 4);
                const float f[8] = {f0.x, f0.y, f0.z, f0.w, f1.x, f1.y, f1.z, f1.w};
                #pragma unroll
                for (int j = 0; j < 8; ++j) h[j] = (short)f2bf(f[j]);
            } else {
                #pragma unroll
                for (int j = 0; j < 8; ++j) h[j] = 0;
            }
            Ah[rt][ks] = h;
        }
    }
}

// -------- sweep 1: MFMA + per-lane fmax only; one reduce+atomicMax/block -----
// grid (NS, 64): x=split -> XCD = split%8 -> split's EH chunk L2-resident.
__global__ __launch_bounds__(256, 3)
void vq_max_kernel(const float* __restrict__ z,
                   const unsigned short* __restrict__ EH,
                   unsigned* __restrict__ rmx) {
    const int tid  = threadIdx.x;
    const int w    = tid >> 6;
    const int lane = tid & 63;
    const int n    = lane & 15;
    const int q    = lane >> 4;
    const int sp   = blockIdx.x;
    const int row0 = blockIdx.y * 64;
    const int c0   = sp * CHUNK;

    bf16x8 Ah[4][5];
    load_A_frags(z, row0, n, q, Ah);

    float ml[16];
    #pragma unroll
    for (int i = 0; i < 16; ++i) ml[i] = -INFINITY;

    const unsigned short* pB = EH + (size_t)(c0 + w * 16 + n) * KPAD + q * 8;
    bf16x8 b[5];
    #pragma unroll
    for (int ks = 0; ks < 5; ++ks) b[ks] = *(const bf16x8*)(pB + ks * 32);

    for (int t = 0; t < NT; ++t) {
        const unsigned short* pN = pB + (size_t)64 * KPAD;
        bf16x8 bn[5];
        #pragma unroll
        for (int ks = 0; ks < 5; ++ks) bn[ks] = *(const bf16x8*)(pN + ks * 32);

        f32x4 acc[4];
        #pragma unroll
        for (int rt = 0; rt < 4; ++rt) { acc[rt][0]=0.f; acc[rt][1]=0.f; acc[rt][2]=0.f; acc[rt][3]=0.f; }
        #pragma unroll
        for (int ks = 0; ks < 5; ++ks)
            #pragma unroll
            for (int rt = 0; rt < 4; ++rt)
                acc[rt] = __builtin_amdgcn_mfma_f32_16x16x32_bf16(Ah[rt][ks], b[ks], acc[rt], 0, 0, 0);

        #pragma unroll
        for (int rt = 0; rt < 4; ++rt)
            #pragma unroll
            for (int r = 0; r < 4; ++r)
                ml[rt*4 + r] = fmaxf(ml[rt*4 + r], acc[rt][r]);

        #pragma unroll
        for (int ks = 0; ks < 5; ++ks) b[ks] = bn[ks];
        pB = pN;
    }

    // reduce over the 16 lanes sharing each row (n bits), once per kernel
    __shared__ float wmax[4][64];
    #pragma unroll
    for (int i = 0; i < 16; ++i) {
        float v = ml[i];
        v = fmaxf(v, __shfl_xor(v, 1, 64));
        v = fmaxf(v, __shfl_xor(v, 2, 64));
        v = fmaxf(v, __shfl_xor(v, 4, 64));
        v = fmaxf(v, __shfl_xor(v, 8, 64));
        if (n == 0) wmax[w][(i >> 2) * 16 + q * 4 + (i & 3)] = v;
    }
    __syncthreads();
    if (tid < 64) {
        const float m = fmaxf(fmaxf(wmax[0][tid], wmax[1][tid]),
                              fmaxf(wmax[2][tid], wmax[3][tid])) * 2.0f;
        atomicMax(&rmx[row0 + tid], fkey(m));
    }
}

// -------- sweep 2: identical MFMA loop; append codes within MARGIN of max ----
__global__ __launch_bounds__(256, 3)
void vq_select_kernel(const float* __restrict__ z,
                      const unsigned short* __restrict__ EH,
                      const unsigned* __restrict__ rmx,
                      int* __restrict__ cnt, int* __restrict__ list) {
    const int tid  = threadIdx.x;
    const int w    = tid >> 6;
    const int lane = tid & 63;
    const int n    = lane & 15;
    const int q    = lane >> 4;
    const int sp   = blockIdx.x;
    const int row0 = blockIdx.y * 64;
    const int c0   = sp * CHUNK;

    bf16x8 Ah[4][5];
    load_A_frags(z, row0, n, q, Ah);

    float thr[16];
    #pragma unroll
    for (int i = 0; i < 16; ++i) {
        const int row = row0 + (i >> 2) * 16 + q * 4 + (i & 3);
        thr[i] = fkey_inv(rmx[row]) - MARGIN;
    }

    const unsigned short* pB = EH + (size_t)(c0 + w * 16 + n) * KPAD + q * 8;
    bf16x8 b[5];
    #pragma unroll
    for (int ks = 0; ks < 5; ++ks) b[ks] = *(const bf16x8*)(pB + ks * 32);

    for (int t = 0; t < NT; ++t) {
        const unsigned short* pN = pB + (size_t)64 * KPAD;
        bf16x8 bn[5];
        #pragma unroll
        for (int ks = 0; ks < 5; ++ks) bn[ks] = *(const bf16x8*)(pN + ks * 32);

        f32x4 acc[4];
        #pragma unroll
        for (int rt = 0; rt < 4; ++rt) { acc[rt][0]=0.f; acc[rt][1]=0.f; acc[rt][2]=0.f; acc[rt][3]=0.f; }
        #pragma unroll
        for (int ks = 0; ks < 5; ++ks)
            #pragma unroll
            for (int rt = 0; rt < 4; ++rt)
                acc[rt] = __builtin_amdgcn_mfma_f32_16x16x32_bf16(Ah[rt][ks], b[ks], acc[rt], 0, 0, 0);

        const int code = c0 + t * 64 + w * 16 + n;
        #pragma unroll
        for (int rt = 0; rt < 4; ++rt)
            #pragma unroll
            for (int r = 0; r < 4; ++r) {
                const float vm = 2.0f * acc[rt][r];
                if (vm >= thr[rt*4 + r] && code < KCODES) {
                    const int row = row0 + rt * 16 + q * 4 + r;
                    const int pos = atomicAdd(&cnt[row], 1);
                    if (pos < CAP) list[(size_t)row * CAP + pos] = code;
                }
            }

        #pragma unroll
        for (int ks = 0; ks < 5; ++ks) b[ks] = bn[ks];
        pB = pN;
    }
}

// ------ phase C: exact fp32 re-eval of candidates, tie-break, gather, loss ---
__global__ void vq_phaseC_kernel(const float* __restrict__ z,
                                 const float* __restrict__ emb,
                                 const int* __restrict__ cnt,
                                 const int* __restrict__ list,
                                 float* __restrict__ out,
                                 float* __restrict__ lrow) {
    const int r   = blockIdx.x;
    const int tid = threadIdx.x;
    const int lane = tid & 63, wid = tid >> 6;
    __shared__ float zs[D];
    __shared__ float As_;
    __shared__ float bd_s[4]; __shared__ int bi_s[4];
    __shared__ int   bc_s;
    __shared__ float ls_s[4];

    if (tid < D) zs[tid] = z[(size_t)r * D + tid];
    __syncthreads();
    if (tid == 0) {
        float s = 0.f;
        for (int k = 0; k < D; ++k) s = fmaf(zs[k], zs[k], s);
        As_ = s;
    }
    __syncthreads();
    const float A = As_;

    const int nc   = cnt[r];
    const bool full = (nc <= 0) || (nc > CAP);
    const int count = full ? KCODES : nc;

    float bd = INFINITY; int bi = 0x7fffffff;
    for (int i = tid; i < count; i += 256) {
        const int c = full ? i : list[(size_t)r * CAP + i];
        const float4* e4 = (const float4*)(emb + (size_t)c * D);
        float acc = 0.f;
        #pragma unroll
        for (int j = 0; j < 36; ++j) {
            const float4 e = e4[j];
            acc = fmaf(zs[4*j],   e.x, acc);
            acc = fmaf(zs[4*j+1], e.y, acc);
            acc = fmaf(zs[4*j+2], e.z, acc);
            acc = fmaf(zs[4*j+3], e.w, acc);
        }
        const float m2 = 2.0f * acc;
        const float d  = A - m2;            // identical to verified R1 arithmetic
        if (d < bd || (d == bd && c < bi)) { bd = d; bi = c; }
    }
    #pragma unroll
    for (int m = 1; m < 64; m <<= 1) {
        const float od = __shfl_xor(bd, m, 64);
        const int   oi = __shfl_xor(bi, m, 64);
        if (od < bd || (od == bd && oi < bi)) { bd = od; bi = oi; }
    }
    if (lane == 0) { bd_s[wid] = bd; bi_s[wid] = bi; }
    __syncthreads();
    if (tid == 0) {
        float fbd = bd_s[0]; int fbi = bi_s[0];
        for (int k = 1; k < 4; ++k) {
            if (bd_s[k] < fbd || (bd_s[k] == fbd && bi_s[k] < fbi)) { fbd = bd_s[k]; fbi = bi_s[k]; }
        }
        bc_s = fbi;
        out[IDX_OFF + r] = (float)fbi;
    }
    __syncthreads();
    const int bc = bc_s;

    float ls = 0.f;
    if (tid < D) {
        const float e = emb[(size_t)bc * D + tid];
        out[(size_t)r * D + tid] = e;
        const float dl = e - zs[tid];
        ls = dl * dl;
    }
    #pragma unroll
    for (int m = 1; m < 64; m <<= 1) ls += __shfl_xor(ls, m, 64);
    if (lane == 0) ls_s[wid] = ls;
    __syncthreads();
    if (tid == 0) lrow[r] = ls_s[0] + ls_s[1] + ls_s[2] + ls_s[3];
}

// ---------------------------- final loss reduce ------------------------------
__global__ void vq_loss_kernel(const float* __restrict__ lrow, float* __restrict__ out) {
    __shared__ float sm[256];
    const int tid = threadIdx.x;
    float s = 0.f;
    for (int i = tid; i < NROWS; i += 256) s += lrow[i];
    sm[tid] = s; __syncthreads();
    for (int st = 128; st > 0; st >>= 1) {
        if (tid < st) sm[tid] += sm[tid + st];
        __syncthreads();
    }
    if (tid == 0) out[LOSS_OFF] = sm[0] / 589824.0f;
}

// ======================= R1 fallback (small-ws path) =========================
#define BM 64
#define BN 64
#define LDP 68
__global__ __launch_bounds__(256, 2)
void vq_argmin_fb(const float* __restrict__ z, const float* __restrict__ emb,
                  float* __restrict__ pd, int* __restrict__ pi) {
    __shared__ float zsm[D][LDP];
    __shared__ float esm[D][LDP];
    __shared__ float Asm[BM];
    const int tid = threadIdx.x;
    const int row0 = blockIdx.x * BM;
    const int sp = blockIdx.y;
    const int c0 = sp * CHUNK;
    const int c1 = (c0 + CHUNK < KCODES) ? (c0 + CHUNK) : KCODES;
    {
        const int r = tid >> 2, p = tid & 3;
        const float4* src = (const float4*)(z + (size_t)(row0 + r) * D);
        #pragma unroll
        for (int i = 0; i < 9; ++i) {
            const int j4 = p + 4 * i;
            const float4 v = src[j4];
            zsm[4*j4+0][r] = v.x; zsm[4*j4+1][r] = v.y;
            zsm[4*j4+2][r] = v.z; zsm[4*j4+3][r] = v.w;
        }
    }
    __syncthreads();
    if (tid < BM) {
        float s = 0.f;
        for (int k = 0; k < D; ++k) { const float t = zsm[k][tid]; s = fmaf(t, t, s); }
        Asm[tid] = s;
    }
    __syncthreads();
    const int tx = tid & 15, ty = tid >> 4;
    float Arow[4];
    #pragma unroll
    for (int i = 0; i < 4; ++i) Arow[i] = Asm[ty*4 + i];
    float bestd[4]; int besti[4];
    #pragma unroll
    for (int i = 0; i < 4; ++i) { bestd[i] = INFINITY; besti[i] = 0x7fffffff; }
    const int ntiles = (c1 - c0 + BN - 1) / BN;
    for (int t = 0; t < ntiles; ++t) {
        const int cb = c0 + t * BN;
        __syncthreads();
        {
            const int cl = tid >> 2, p = tid & 3;
            int crow = cb + cl; if (crow >= KCODES) crow = KCODES - 1;
            const float4* src = (const float4*)(emb + (size_t)crow * D);
            #pragma unroll
            for (int i = 0; i < 9; ++i) {
                const int j4 = p + 4 * i;
                const float4 v = src[j4];
                esm[4*j4+0][cl] = v.x; esm[4*j4+1][cl] = v.y;
                esm[4*j4+2][cl] = v.z; esm[4*j4+3][cl] = v.w;
            }
        }
        __syncthreads();
        float acc[4][4];
        #pragma unroll
        for (int i = 0; i < 4; ++i)
            #pragma unroll
            for (int j = 0; j < 4; ++j) acc[i][j] = 0.f;
        #pragma unroll 4
        for (int k = 0; k < D; ++k) {
            const float4 a = *(const float4*)&zsm[k][ty*4];
            const float4 b = *(const float4*)&esm[k][tx*4];
            acc[0][0]=fmaf(a.x,b.x,acc[0][0]); acc[0][1]=fmaf(a.x,b.y,acc[0][1]);
            acc[0][2]=fmaf(a.x,b.z,acc[0][2]); acc[0][3]=fmaf(a.x,b.w,acc[0][3]);
            acc[1][0]=fmaf(a.y,b.x,acc[1][0]); acc[1][1]=fmaf(a.y,b.y,acc[1][1]);
            acc[1][2]=fmaf(a.y,b.z,acc[1][2]); acc[1][3]=fmaf(a.y,b.w,acc[1][3]);
            acc[2][0]=fmaf(a.z,b.x,acc[2][0]); acc[2][1]=fmaf(a.z,b.y,acc[2][1]);
            acc[2][2]=fmaf(a.z,b.z,acc[2][2]); acc[2][3]=fmaf(a.z,b.w,acc[2][3]);
            acc[3][0]=fmaf(a.w,b.x,acc[3][0]); acc[3][1]=fmaf(a.w,b.y,acc[3][1]);
            acc[3][2]=fmaf(a.w,b.z,acc[3][2]); acc[3][3]=fmaf(a.w,b.w,acc[3][3]);
        }
        #pragma unroll
        for (int j = 0; j < 4; ++j) {
            const int code = cb + tx*4 + j;
            if (code < c1) {
                #pragma unroll
                for (int i = 0; i < 4; ++i) {
                    const float m2 = 2.0f * acc[i][j];
                    const float d  = Arow[i] - m2;
                    if (d < bestd[i] || (d == bestd[i] && code < besti[i])) {
                        bestd[i] = d; besti[i] = code;
                    }
                }
            }
        }
    }
    #pragma unroll
    for (int i = 0; i < 4; ++i) {
        float d = bestd[i]; int idx = besti[i];
        #pragma unroll
        for (int m = 1; m < 16; m <<= 1) {
            const float od = __shfl_xor(d, m, 64);
            const int   oi = __shfl_xor(idx, m, 64);
            if (od < d || (od == d && oi < idx)) { d = od; idx = oi; }
        }
        if (tx == 0) {
            const int r = row0 + ty*4 + i;
            pd[(size_t)sp * NROWS + r] = d;
            pi[(size_t)sp * NROWS + r] = idx;
        }
    }
}

__global__ void vq_finalize_fb(const float* __restrict__ z, const float* __restrict__ emb,
                               const float* __restrict__ pd, const int* __restrict__ pi,
                               float* __restrict__ out, float* __restrict__ lrow) {
    const int r = blockIdx.x * blockDim.x + threadIdx.x;
    if (r >= NROWS) return;
    float bd = INFINITY; int bi = 0x7fffffff;
    for (int s = 0; s < NS; ++s) {
        const float d = pd[(size_t)s * NROWS + r];
        const int  ix = pi[(size_t)s * NROWS + r];
        if (d < bd || (d == bd && ix < bi)) { bd = d; bi = ix; }
    }
    out[IDX_OFF + r] = (float)bi;
    const float4* e4 = (const float4*)(emb + (size_t)bi * D);
    const float4* z4 = (const float4*)(z + (size_t)r * D);
    float4* o4 = (float4*)(out + (size_t)r * D);
    float ls = 0.f;
    #pragma unroll
    for (int j = 0; j < 36; ++j) {
        const float4 e = e4[j], zz = z4[j];
        o4[j] = e;
        const float dx = e.x - zz.x, dy = e.y - zz.y;
        const float dz_ = e.z - zz.z, dw = e.w - zz.w;
        ls += dx*dx + dy*dy + dz_*dz_ + dw*dw;
    }
    lrow[r] = ls;
}

// ------------------------------- launch --------------------------------------
extern "C" void kernel_launch(void* const* d_in, const int* in_sizes, int n_in,
                              void* d_out, int out_size, void* d_ws, size_t ws_size,
                              hipStream_t stream) {
    const float* z   = (const float*)d_in[0];
    const float* emb = (const float*)d_in[1];
    float* out = (float*)d_out;

    if (ws_size >= WS_NEED) {
        unsigned short* EH  = (unsigned short*)((char*)d_ws + EH_OFF);
        int*      cnt  = (int*)((char*)d_ws + CNT_OFF);
        unsigned* rmx  = (unsigned*)((char*)d_ws + RMX_OFF);
        int*      list = (int*)((char*)d_ws + LIST_OFF);
        float*    lrow = (float*)((char*)d_ws + LROW_OFF);

        prep_emb_kernel<<<(EHROWS * 20 + 255) / 256, 256, 0, stream>>>(emb, EH);
        zero_ws_kernel<<<(NROWS + 255) / 256, 256, 0, stream>>>(cnt, rmx);
        dim3 gs(NS, 64);   // x=split -> XCD affinity for EH chunks
        vq_max_kernel<<<gs, 256, 0, stream>>>(z, EH, rmx);
        vq_select_kernel<<<gs, 256, 0, stream>>>(z, EH, rmx, cnt, list);
        vq_phaseC_kernel<<<NROWS, 256, 0, stream>>>(z, emb, cnt, list, out, lrow);
        vq_loss_kernel<<<1, 256, 0, stream>>>(lrow, out);
    } else {
        float* pd   = (float*)d_ws;
        int*   pi   = (int*)((char*)d_ws + (size_t)NS * NROWS * 4);
        float* lrow = (float*)((char*)d_ws + (size_t)NS * NROWS * 8);
        dim3 g1(64, NS);
        vq_argmin_fb<<<g1, 256, 0, stream>>>(z, emb, pd, pi);
        vq_finalize_fb<<<16, 256, 0, stream>>>(z, emb, pd, pi, out, lrow);
        vq_loss_kernel<<<1, 256, 0, stream>>>(lrow, out);
    }
}